// Round 10
// baseline (280.035 us; speedup 1.0000x reference)
//
#include <hip/hip_runtime.h>
#include <stdint.h>

#define EMB    32
#define BATCH  128
#define NU     200000
#define KSEL   50000
#define XCOLS  33
#define SLOTS  32         // fallback sweep2 LDS cand slots (u64)
#define DSLOTS 16         // digit sweep2 LDS cand slots (u32)
#define G1     512
#define G2D    512
#define G2P    512
#define G2F    256
#define HISTW  (128 * 129)
#define T1     32
#define T2     64

// ws layout (fixed small area)
#define OFF_SPRE   0
#define OFF_IIDE   16384
#define OFF_GHIST  32768
#define OFF_BASE16 163840
#define OFF_PREFIX 164352
#define OFF_M2     164864
#define OFF_EQ     165376
#define OFF_BIG    173568
#define PART_BYTES ((size_t)G1 * HISTW * 4)            // 33,816,576
// digit mode big-region layout
#define DIG_BYTES  ((size_t)NU * 128 * 2)              // 51,200,000
#define OFF_PARTD  ((size_t)OFF_BIG + DIG_BYTES)
#define OFF_CANDD  (OFF_PARTD + PART_BYTES)

// lane^1 exchange via DPP quad_perm [1,0,3,2] (fallback sweep2 only)
__device__ __forceinline__ float xor1(float x) {
    int r = __builtin_amdgcn_update_dpp(0, __float_as_int(x), 0xB1, 0xF, 0xF, true);
    return __int_as_float(r);
}

// THE shared dot: identical FMA chain everywhere => bit-identical keys
__device__ __forceinline__ float dotrow(const float* __restrict__ c,
                                        const float* __restrict__ u) {
    float d = 0.f;
    #pragma unroll
    for (int q = 0; q < 8; ++q) {
        const float4 v = *(const float4*)(u + q * 4);
        d += c[4*q+0]*v.x + c[4*q+1]*v.y + c[4*q+2]*v.z + c[4*q+3]*v.w;
    }
    return d;
}

// ---------------- prep ----------------
__global__ void prep_kernel(const float* __restrict__ x,
                            const float* __restrict__ iid_w,
                            const float* __restrict__ rp,
                            const float* __restrict__ uid,
                            float* __restrict__ s_pre,
                            float* __restrict__ iid_emb,
                            uint32_t* __restrict__ base16,
                            uint32_t* __restrict__ eq_cnt) {
    const int b = blockIdx.x;
    const int t = threadIdx.x;          // 64 threads
    __shared__ float xr[EMB];
    if (t < EMB) xr[t] = x[b * XCOLS + 1 + t];
    if (t == 63) eq_cnt[b * 16] = 0u;
    __syncthreads();
    if (t < EMB) {
        float acc = 0.f;
        #pragma unroll
        for (int k = 0; k < EMB; ++k) acc += xr[k] * rp[t * EMB + k];
        s_pre[b * EMB + t] = acc;
    } else {
        const int d = t - EMB;
        const int iid = (int)x[b * XCOLS];
        iid_emb[b * EMB + d] = iid_w[(size_t)iid * EMB + d];
    }
    __syncthreads();
    if (t == 0) {
        float dot = 0.f;
        #pragma unroll
        for (int k = 0; k < EMB; ++k) dot += s_pre[b * EMB + k] * uid[k];
        const uint32_t bits = __float_as_uint(fabsf(dot - 4.0f));
        const uint32_t hi = bits >> 16;
        base16[b] = (hi > 128u) ? (hi - 128u) : 0u;
    }
}

// ---------------- zero scratch (atomic-fallback path only) ----------------
__global__ void zero_kernel(uint32_t* __restrict__ p, int n) {
    int i = blockIdx.x * blockDim.x + threadIdx.x;
    if (i < n) p[i] = 0u;
}

// ---------------- sweep1: LDS-tile broadcast key dot, packed-u16 hist, digit store ----
template <bool PART, bool DIG>
__global__ __launch_bounds__(1024)
void sweep1_kernel(const float* __restrict__ s_pre,
                   const float* __restrict__ uid,
                   const uint32_t* __restrict__ base16,
                   uint32_t* __restrict__ gout,
                   uint16_t* __restrict__ dig,
                   int jchunk) {
    extern __shared__ uint32_t smem1[];
    uint32_t* hist = smem1;                         // HISTW words
    float* tiles = (float*)(smem1 + HISTW);         // [2][T1*EMB]
    const int t  = threadIdx.x;
    const int b  = t & 127;
    const int jl = t >> 7;               // 0..7
    for (int i = t; i < HISTW; i += 1024) hist[i] = 0u;
    float s[EMB];
    #pragma unroll
    for (int d = 0; d < EMB; ++d) s[d] = s_pre[b * EMB + d];
    const uint32_t base = base16[b];

    const int j0 = blockIdx.x * jchunk;
    const int jend = min(j0 + jchunk, NU);
    const int nt = (jend - j0 + T1 - 1) / T1;
    const int srow = t >> 5;

    {   // stage tile 0
        float v = 0.f;
        if (j0 + srow < NU) v = uid[(size_t)j0 * EMB + t];
        tiles[t] = v;
    }
    __syncthreads();

    for (int tt = 0; tt < nt; ++tt) {
        const int jt = j0 + tt * T1;
        const bool has_next = (tt + 1 < nt);
        float vnext = 0.f;
        if (has_next) {
            const int jn = jt + T1;
            if (jn + srow < NU) vnext = uid[(size_t)jn * EMB + t];
        }
        const float* tp = tiles + (tt & 1) * (T1 * EMB);
        const int lim = min(T1, jend - jt);
        for (int r = jl; r < lim; r += 8) {
            const float d0 = dotrow(s, tp + r * EMB);
            const uint32_t bits0 = __float_as_uint(fabsf(d0 - 4.0f));
            const uint32_t hi = bits0 >> 16;
            if (DIG) dig[(size_t)(jt + r) * 128 + b] = (uint16_t)hi;
            int dg0 = (int)hi - (int)base;
            dg0 = dg0 < 0 ? 0 : (dg0 > 255 ? 255 : dg0);
            atomicAdd(&hist[b * 129 + (dg0 >> 1)], 1u << ((dg0 & 1) * 16));
        }
        if (has_next) {
            tiles[((tt + 1) & 1) * (T1 * EMB) + t] = vnext;
        }
        __syncthreads();
    }
    if (PART) {
        uint32_t* part = gout + (size_t)blockIdx.x * HISTW;
        for (int i = t; i < HISTW; i += 1024) part[i] = hist[i];
    } else {
        for (int i = t; i < 128 * 256; i += 1024) {
            const int r = i >> 8, d = i & 255;
            const uint32_t c = (hist[r * 129 + (d >> 1)] >> ((d & 1) * 16)) & 0xFFFFu;
            if (c) atomicAdd(&gout[i], c);
        }
    }
}

// ---------------- scan1 (atomic fallback) ----------------
__global__ void scan1_kernel(const uint32_t* __restrict__ ghist,
                             const uint32_t* __restrict__ base16,
                             uint32_t* __restrict__ prefix16,
                             uint32_t* __restrict__ m2) {
    const int b = threadIdx.x;           // 128 threads, 1 block
    uint32_t cum = 0, before = 0;
    int c1 = 255;
    for (int d = 0; d < 256; ++d) {
        const uint32_t c = ghist[b * 256 + d];
        if (cum + c >= (uint32_t)KSEL) { c1 = d; before = cum; break; }
        cum += c;
        if (d == 255) before = cum;
    }
    prefix16[b] = base16[b] + (uint32_t)c1;
    m2[b] = (uint32_t)KSEL - before;
}

// ---------------- scan1 (part path) ----------------
__global__ __launch_bounds__(256)
void scan1_part_kernel(const uint32_t* __restrict__ part,
                       const uint32_t* __restrict__ base16,
                       uint32_t* __restrict__ prefix16,
                       uint32_t* __restrict__ m2) {
    const int row = blockIdx.x;          // 128 blocks
    const int t = threadIdx.x;           // 256 threads = digits
    __shared__ uint32_t h[256];
    const int sh = (t & 1) * 16;
    const uint32_t* p = part + (size_t)row * 129 + (t >> 1);
    uint32_t a0 = 0, a1 = 0, a2 = 0, a3 = 0;
    for (int g = 0; g < G1; g += 4) {
        a0 += (p[(size_t)(g + 0) * HISTW] >> sh) & 0xFFFFu;
        a1 += (p[(size_t)(g + 1) * HISTW] >> sh) & 0xFFFFu;
        a2 += (p[(size_t)(g + 2) * HISTW] >> sh) & 0xFFFFu;
        a3 += (p[(size_t)(g + 3) * HISTW] >> sh) & 0xFFFFu;
    }
    h[t] = a0 + a1 + a2 + a3;
    __syncthreads();
    if (t == 0) {
        uint32_t cum = 0, before = 0; int c1 = 255;
        for (int d = 0; d < 256; ++d) {
            const uint32_t c = h[d];
            if (cum + c >= (uint32_t)KSEL) { c1 = d; before = cum; break; }
            cum += c;
            if (d == 255) before = cum;
        }
        prefix16[row] = base16[row] + (uint32_t)c1;
        m2[row] = (uint32_t)KSEL - before;
    }
}

// ---------------- sweep2 digit mode: val-dot only, digit compare ----------
__global__ __launch_bounds__(1024)
void sweep2_dig_kernel(const float* __restrict__ iid_emb,
                       const float* __restrict__ uid,
                       const uint16_t* __restrict__ dig,
                       const uint32_t* __restrict__ prefix16,
                       uint32_t* __restrict__ eq_cnt,
                       float* __restrict__ sum_part,
                       uint64_t* __restrict__ cand,
                       int cap, int jchunk) {
    __shared__ uint32_t lcand[128 * DSLOTS];     // 8 KB
    __shared__ float tiles[2][T2 * EMB];         // 16 KB
    __shared__ uint32_t lcnt[128];
    __shared__ uint32_t lbase[128];
    __shared__ float sums[1024];
    const int t  = threadIdx.x;
    const int b  = t & 127;
    const int jl = t >> 7;               // 0..7
    if (t < 128) lcnt[t] = 0u;
    float e[EMB];
    {
        const float4* ep4 = (const float4*)(iid_emb + b * EMB);
        #pragma unroll
        for (int q = 0; q < 8; ++q) {
            float4 v = ep4[q];
            e[4*q+0]=v.x; e[4*q+1]=v.y; e[4*q+2]=v.z; e[4*q+3]=v.w;
        }
    }
    const int pfx = (int)prefix16[b];

    const int j0 = blockIdx.x * jchunk;
    const int jend = min(j0 + jchunk, NU);
    const int nt = (jend - j0 + T2 - 1) / T2;
    const int srow = t >> 4;

    {   // stage tile 0
        float2 v = make_float2(0.f, 0.f);
        if (j0 + srow < NU) v = *(const float2*)(uid + (size_t)j0 * EMB + t * 2);
        *(float2*)(&tiles[0][0] + t * 2) = v;
    }
    __syncthreads();

    float local = 0.f;
    for (int tt = 0; tt < nt; ++tt) {
        const int jt = j0 + tt * T2;
        const bool has_next = (tt + 1 < nt);
        float2 vnext = make_float2(0.f, 0.f);
        if (has_next) {
            const int jn = jt + T2;
            if (jn + srow < NU) vnext = *(const float2*)(uid + (size_t)jn * EMB + t * 2);
        }
        const float* tp = &tiles[tt & 1][0];
        const int lim = min(T2, jend - jt);
        for (int r = jl; r < lim; r += 8) {
            const int hi = (int)dig[(size_t)(jt + r) * 128 + b];
            const float dv = dotrow(e, tp + r * EMB);
            local += (hi < pfx) ? dv : 0.f;
            if (hi == pfx) {
                const uint32_t pos = atomicAdd(&lcnt[b], 1u);
                const uint32_t jj = (uint32_t)(jt + r);
                if (pos < (uint32_t)DSLOTS) lcand[b * DSLOTS + pos] = jj;
                else {
                    const uint32_t g = atomicAdd(&eq_cnt[b * 16], 1u);
                    if (g < (uint32_t)cap) cand[(size_t)b * cap + g] = (uint64_t)jj;
                }
            }
        }
        if (has_next) {
            *(float2*)(&tiles[(tt + 1) & 1][0] + t * 2) = vnext;
        }
        __syncthreads();
    }
    sums[t] = local;                     // t = jl*128 + b
    __syncthreads();
    if (t < 128) {
        float acc = 0.f;
        #pragma unroll
        for (int l = 0; l < 8; ++l) acc += sums[l * 128 + t];
        sum_part[(size_t)blockIdx.x * 128 + t] = acc;
        const uint32_t n = min(lcnt[t], (uint32_t)DSLOTS);
        lbase[t] = atomicAdd(&eq_cnt[t * 16], n);
    }
    __syncthreads();
    for (int i = t; i < 128 * DSLOTS; i += 1024) {
        const int bb = i >> 4;           // DSLOTS == 16
        const int sl = i & 15;
        if (sl < (int)min(lcnt[bb], (uint32_t)DSLOTS)) {
            const uint32_t p = lbase[bb] + (uint32_t)sl;
            if (p < (uint32_t)cap) cand[(size_t)bb * cap + p] = (uint64_t)lcand[i];
        }
    }
}

// ---------------- sweep2 fallback (R9 role-split) ----------
__global__ __launch_bounds__(1024)
void sweep2_fb_kernel(const float* __restrict__ s_pre,
                      const float* __restrict__ iid_emb,
                      const float* __restrict__ uid,
                      const uint32_t* __restrict__ prefix16,
                      uint32_t* __restrict__ eq_cnt,
                      float* __restrict__ sum_part,
                      uint64_t* __restrict__ cand,
                      int cap, int jchunk) {
    extern __shared__ char smem2[];
    uint64_t* lcand  = (uint64_t*)smem2;                   // 128*32*8 = 32768
    float*    tiles  = (float*)(smem2 + 32768);            // 16384
    uint32_t* lcnt   = (uint32_t*)(smem2 + 49152);
    uint32_t* lbase  = (uint32_t*)(smem2 + 49664);
    float*    sums_b = (float*)(smem2 + 50176);
    const int t   = threadIdx.x;
    const int par = t & 1;
    const int pr  = t >> 1;
    const int b   = pr & 127;
    const int jl  = pr >> 7;
    if (t < 128) { lcnt[t] = 0u; sums_b[t] = 0.f; }
    float c[EMB];
    {
        const float4* cp4 = (const float4*)((par ? iid_emb : s_pre) + b * EMB);
        #pragma unroll
        for (int q = 0; q < 8; ++q) {
            float4 v = cp4[q];
            c[4*q+0] = v.x; c[4*q+1] = v.y; c[4*q+2] = v.z; c[4*q+3] = v.w;
        }
    }
    const uint32_t pfx = prefix16[b];

    const int j0 = blockIdx.x * jchunk;
    const int jend = min(j0 + jchunk, NU);
    const int nt = (jend - j0 + T2 - 1) / T2;
    const int srow = t >> 4;

    {
        float2 v = make_float2(0.f, 0.f);
        if (j0 + srow < NU) v = *(const float2*)(uid + (size_t)j0 * EMB + t * 2);
        *(float2*)(tiles + t * 2) = v;
    }
    __syncthreads();

    float local = 0.f;
    for (int tt = 0; tt < nt; ++tt) {
        const int jt = j0 + tt * T2;
        const bool has_next = (tt + 1 < nt);
        float2 vnext = make_float2(0.f, 0.f);
        if (has_next) {
            const int jn = jt + T2;
            if (jn + srow < NU) vnext = *(const float2*)(uid + (size_t)jn * EMB + t * 2);
        }
        const float* tp = tiles + (tt & 1) * (T2 * EMB);
        const int lim = min(T2, jend - jt);
        for (int r = jl; r < lim; r += 4) {
            const float a0 = dotrow(c, tp + r * EMB);
            const float p0 = xor1(a0);
            if (par == 0) {
                const uint32_t bits0 = __float_as_uint(fabsf(a0 - 4.0f));
                const uint32_t hi0 = bits0 >> 16;
                local += (hi0 < pfx) ? p0 : 0.f;
                if (hi0 == pfx) {
                    const uint32_t pos = atomicAdd(&lcnt[b], 1u);
                    const uint64_t pk = ((uint64_t)bits0 << 32) | (uint32_t)(jt + r);
                    if (pos < (uint32_t)SLOTS) lcand[b * SLOTS + pos] = pk;
                    else {
                        const uint32_t g = atomicAdd(&eq_cnt[b * 16], 1u);
                        if (g < (uint32_t)cap) cand[(size_t)b * cap + g] = pk;
                    }
                }
            }
        }
        if (has_next) {
            *(float2*)(tiles + ((tt + 1) & 1) * (T2 * EMB) + t * 2) = vnext;
        }
        __syncthreads();
    }
    if (par == 0 && local != 0.f) atomicAdd(&sums_b[b], local);
    __syncthreads();
    if (t < 128) {
        sum_part[(size_t)blockIdx.x * 128 + t] = sums_b[t];
        const uint32_t n = min(lcnt[t], (uint32_t)SLOTS);
        lbase[t] = atomicAdd(&eq_cnt[t * 16], n);
    }
    __syncthreads();
    for (int i = t; i < 128 * SLOTS; i += 1024) {
        const int bb = i >> 5;
        const int sl = i & 31;
        if (sl < (int)min(lcnt[bb], (uint32_t)SLOTS)) {
            const uint32_t p = lbase[bb] + (uint32_t)sl;
            if (p < (uint32_t)cap) cand[(size_t)bb * cap + p] = lcand[i];
        }
    }
}

// ---------------- finalize ----------------
__global__ __launch_bounds__(256)
void final_kernel(const float* __restrict__ iid_emb,
                  const float* __restrict__ s_pre,
                  const float* __restrict__ uid,
                  const uint32_t* __restrict__ m2_,
                  const uint32_t* __restrict__ eq_cnt,
                  const float* __restrict__ sum_part,
                  uint64_t* __restrict__ cand,
                  int cap, int g2, int recompute,
                  float* __restrict__ out) {
    const int b = blockIdx.x;
    const int t = threadIdx.x;           // 256 threads
    __shared__ float red[256];
    __shared__ uint32_t hist[256];
    __shared__ float e[EMB];
    __shared__ float sarr[EMB];
    __shared__ uint32_t tie[128];
    __shared__ uint32_t tiecnt, sc2, sm3, sc3, sm4;
    __shared__ float sbelow;
    if (t < EMB) { e[t] = iid_emb[b * EMB + t]; sarr[t] = s_pre[b * EMB + t]; }
    if (t == 0) tiecnt = 0u;
    hist[t] = 0u;
    {
        float acc = 0.f;
        for (int g = t; g < g2; g += 256) acc += sum_part[(size_t)g * 128 + b];
        red[t] = acc;
    }
    __syncthreads();
    for (int s = 128; s > 0; s >>= 1) { if (t < s) red[t] += red[t + s]; __syncthreads(); }
    if (t == 0) sbelow = red[0];
    __syncthreads();

    const uint32_t ec = eq_cnt[b * 16];
    const int cnt = (int)(ec < (uint32_t)cap ? ec : (uint32_t)cap);
    uint64_t* cb = cand + (size_t)b * cap;

    if (recompute) {   // phase 0: exact bits per candidate (same dotrow chain as sweep1)
        for (int i = t; i < cnt; i += 256) {
            const uint32_t j = (uint32_t)cb[i];
            const float d = dotrow(sarr, uid + (size_t)j * EMB);
            const uint32_t bits = __float_as_uint(fabsf(d - 4.0f));
            cb[i] = ((uint64_t)bits << 32) | j;
        }
        __syncthreads();
    }

    for (int i = t; i < cnt; i += 256) {
        const uint32_t low16 = (uint32_t)(cb[i] >> 32) & 0xFFFFu;
        atomicAdd(&hist[low16 >> 8], 1u);
    }
    __syncthreads();
    if (t == 0) {
        const uint32_t m2v = m2_[b];
        uint32_t cum = 0, before = 0; int c2 = 255;
        for (int d = 0; d < 256; ++d) {
            const uint32_t c = hist[d];
            if (cum + c >= m2v) { c2 = d; before = cum; break; }
            cum += c;
        }
        sc2 = (uint32_t)c2; sm3 = m2v - before;
    }
    __syncthreads();
    const uint32_t c2 = sc2;
    hist[t] = 0u;
    __syncthreads();

    for (int i = t; i < cnt; i += 256) {
        const uint32_t low16 = (uint32_t)(cb[i] >> 32) & 0xFFFFu;
        if ((low16 >> 8) == c2) atomicAdd(&hist[low16 & 255u], 1u);
    }
    __syncthreads();
    if (t == 0) {
        const uint32_t m3 = sm3;
        uint32_t cum = 0, before = 0; int c3 = 255;
        for (int d = 0; d < 256; ++d) {
            const uint32_t c = hist[d];
            if (cum + c >= m3) { c3 = d; before = cum; break; }
            cum += c;
        }
        sc3 = (uint32_t)c3; sm4 = m3 - before;
    }
    __syncthreads();
    const uint32_t T16 = (c2 << 8) | sc3;

    float local = 0.f;
    for (int i = t; i < cnt; i += 256) {
        const uint64_t cv = cb[i];
        const uint32_t low16 = (uint32_t)(cv >> 32) & 0xFFFFu;
        if (low16 < T16) {
            const uint32_t j = (uint32_t)cv;
            const float4* u4 = (const float4*)(uid + (size_t)j * EMB);
            float dv = 0.f;
            #pragma unroll
            for (int q = 0; q < 8; ++q) {
                float4 u = u4[q];
                dv += e[4*q+0]*u.x + e[4*q+1]*u.y + e[4*q+2]*u.z + e[4*q+3]*u.w;
            }
            local += dv;
        } else if (low16 == T16) {
            const uint32_t pos = atomicAdd(&tiecnt, 1u);
            if (pos < 128u) tie[pos] = (uint32_t)cv;
        }
    }
    red[t] = local;
    __syncthreads();
    for (int s = 128; s > 0; s >>= 1) { if (t < s) red[t] += red[t + s]; __syncthreads(); }
    if (t == 0) {
        int tc = (int)(tiecnt < 128u ? tiecnt : 128u);
        for (int i = 1; i < tc; ++i) {
            const uint32_t v = tie[i]; int k = i - 1;
            while (k >= 0 && tie[k] > v) { tie[k+1] = tie[k]; --k; }
            tie[k+1] = v;
        }
        const int m4 = (int)sm4;
        float tsum = 0.f;
        for (int i = 0; i < m4 && i < tc; ++i) {
            const uint32_t j = tie[i];
            float dv = 0.f;
            for (int d = 0; d < EMB; ++d) dv += e[d] * uid[(size_t)j * EMB + d];
            tsum += dv;
        }
        out[b] = (sbelow + red[0] + tsum) / (float)KSEL;
    }
}

extern "C" void kernel_launch(void* const* d_in, const int* in_sizes, int n_in,
                              void* d_out, int out_size, void* d_ws, size_t ws_size,
                              hipStream_t stream) {
    const float* x     = (const float*)d_in[0];
    const float* uid   = (const float*)d_in[1];
    const float* iid_w = (const float*)d_in[2];
    const float* rp    = (const float*)d_in[3];
    float* out = (float*)d_out;

    char* ws = (char*)d_ws;
    float*    s_pre    = (float*)(ws + OFF_SPRE);
    float*    iid_emb  = (float*)(ws + OFF_IIDE);
    uint32_t* ghist    = (uint32_t*)(ws + OFF_GHIST);
    uint32_t* base16   = (uint32_t*)(ws + OFF_BASE16);
    uint32_t* prefix16 = (uint32_t*)(ws + OFF_PREFIX);
    uint32_t* m2       = (uint32_t*)(ws + OFF_M2);
    uint32_t* eq_cnt   = (uint32_t*)(ws + OFF_EQ);

    const bool use_dig  = ws_size >= OFF_CANDD + (size_t)128 * 2048 * 8;
    const bool use_part = !use_dig &&
                          ws_size >= (size_t)OFF_BIG + PART_BYTES + (size_t)128 * 8 * 4096;

    prep_kernel<<<BATCH, 64, 0, stream>>>(x, iid_w, rp, uid, s_pre, iid_emb, base16, eq_cnt);

    const int jc1 = (NU + G1 - 1) / G1;                 // 391
    const size_t lds1 = HISTW * 4 + 2 * T1 * EMB * 4;   // 74240

    if (use_dig) {
        uint16_t* dig      = (uint16_t*)(ws + OFF_BIG);
        uint32_t* part     = (uint32_t*)(ws + OFF_PARTD);
        float*    sum_part = (float*)(ws + OFF_PARTD);  // overlay after scan1_part
        uint64_t* cand     = (uint64_t*)(ws + OFF_CANDD);
        long long cap_ll = ((long long)ws_size - (long long)OFF_CANDD) / (128LL * 8LL);
        int cap = (int)(cap_ll > 16384 ? 16384 : cap_ll);

        sweep1_kernel<true, true><<<G1, 1024, lds1, stream>>>(s_pre, uid, base16, part, dig, jc1);
        scan1_part_kernel<<<BATCH, 256, 0, stream>>>(part, base16, prefix16, m2);

        const int jc2 = (NU + G2D - 1) / G2D;           // 391
        sweep2_dig_kernel<<<G2D, 1024, 0, stream>>>(iid_emb, uid, dig, prefix16,
                                                    eq_cnt, sum_part, cand, cap, jc2);

        final_kernel<<<BATCH, 256, 0, stream>>>(iid_emb, s_pre, uid, m2, eq_cnt, sum_part,
                                                cand, cap, G2D, 1, out);
    } else if (use_part) {
        uint32_t* part     = (uint32_t*)(ws + OFF_BIG);
        float*    sum_part = (float*)(ws + OFF_BIG);    // overlay after scan1_part
        uint64_t* cand     = (uint64_t*)(ws + OFF_BIG + PART_BYTES);
        long long cap_ll = ((long long)ws_size - (long long)(OFF_BIG + PART_BYTES)) / (128LL * 8LL);
        int cap = (int)(cap_ll > 16384 ? 16384 : cap_ll);

        sweep1_kernel<true, false><<<G1, 1024, lds1, stream>>>(s_pre, uid, base16, part, nullptr, jc1);
        scan1_part_kernel<<<BATCH, 256, 0, stream>>>(part, base16, prefix16, m2);

        const int jc2 = (NU + G2P - 1) / G2P;
        const size_t lds2 = 32768 + 16384 + 1536;
        sweep2_fb_kernel<<<G2P, 1024, lds2, stream>>>(s_pre, iid_emb, uid, prefix16,
                                                      eq_cnt, sum_part, cand, cap, jc2);

        final_kernel<<<BATCH, 256, 0, stream>>>(iid_emb, s_pre, uid, m2, eq_cnt, sum_part,
                                                cand, cap, G2P, 0, out);
    } else {
        uint64_t* cand     = (uint64_t*)(ws + OFF_BIG);
        float*    sum_part = (float*)(ws + OFF_GHIST);  // overlay after scan1
        long long cap_ll = ((long long)ws_size - OFF_BIG) / (128LL * 8LL);
        int cap = (int)(cap_ll > 16384 ? 16384 : (cap_ll < 1 ? 1 : cap_ll));

        const int n = (OFF_BIG - OFF_GHIST) / 4;
        zero_kernel<<<(n + 255) / 256, 256, 0, stream>>>((uint32_t*)(ws + OFF_GHIST), n);

        sweep1_kernel<false, false><<<G1, 1024, lds1, stream>>>(s_pre, uid, base16, ghist, nullptr, jc1);
        scan1_kernel<<<1, 128, 0, stream>>>(ghist, base16, prefix16, m2);

        const int jc2 = (NU + G2F - 1) / G2F;
        const size_t lds2 = 32768 + 16384 + 1536;
        sweep2_fb_kernel<<<G2F, 1024, lds2, stream>>>(s_pre, iid_emb, uid, prefix16,
                                                      eq_cnt, sum_part, cand, cap, jc2);

        final_kernel<<<BATCH, 256, 0, stream>>>(iid_emb, s_pre, uid, m2, eq_cnt, sum_part,
                                                cand, cap, G2F, 0, out);
    }
}